// Round 2
// baseline (488.930 us; speedup 1.0000x reference)
//
#include <hip/hip_runtime.h>

#define NPOS 8192
#define NC 64
#define NB 4
#define NSPLIT 4
#define NCHUNK (NPOS / NSPLIT)
// q pre-scaled by (1/128)*log2(e) so softmax weight = exp2(mfma output)
#define QSCALE 0.01127105500167846f

typedef __bf16 bf16x8 __attribute__((ext_vector_type(8)));
typedef float f32x4 __attribute__((ext_vector_type(4)));

#if defined(__has_builtin)
#if __has_builtin(__builtin_amdgcn_exp2f)
#define EXP2F(x) __builtin_amdgcn_exp2f(x)
#else
#define EXP2F(x) __expf((x) * 0.6931471805599453f)
#endif
#else
#define EXP2F(x) __expf((x) * 0.6931471805599453f)
#endif

static __device__ __forceinline__ unsigned f2bf_u(float x) {
  unsigned u = __float_as_uint(x);
  return (u + 0x7FFFu + ((u >> 16) & 1u)) >> 16;
}
static __device__ __forceinline__ unsigned pack2(float a, float b) {
  return f2bf_u(a) | (f2bf_u(b) << 16);
}

// Stage 1: 1x1 conv projections. q,k -> [B][N][C] bf16 (position-major),
// v -> [B][C][N] bf16 + fp32. q additionally scaled by QSCALE.
__global__ __launch_bounds__(256) void proj_kernel(
    const float* __restrict__ xq, const float* __restrict__ xk, const float* __restrict__ xv,
    const float* __restrict__ Wq, const float* __restrict__ bq,
    const float* __restrict__ Wk, const float* __restrict__ bk,
    const float* __restrict__ Wv, const float* __restrict__ bv,
    unsigned short* __restrict__ qT, unsigned short* __restrict__ kT,
    unsigned short* __restrict__ vb, float* __restrict__ vf)
{
  __shared__ float sW[NC * NC];
  __shared__ float sB[NC];
  const int p = blockIdx.z, b = blockIdx.y;
  const int n0 = blockIdx.x * 256;
  const int tid = threadIdx.x;
  const int wv = tid >> 6, l = tid & 63;

  const float* x    = p == 0 ? xq : (p == 1 ? xk : xv);
  const float* W    = p == 0 ? Wq : (p == 1 ? Wk : Wv);
  const float* bias = p == 0 ? bq : (p == 1 ? bk : bv);

  for (int i = tid; i < NC * NC; i += 256) sW[i] = W[i];
  if (tid < NC) sB[tid] = bias[tid];
  __syncthreads();

  const int nb = n0 + 4 * l;
  const float* xb = x + (size_t)b * NC * NPOS + nb;

  float acc[16][4];
#pragma unroll
  for (int oi = 0; oi < 16; ++oi) {
    float bz = sB[16 * wv + oi];
    acc[oi][0] = bz; acc[oi][1] = bz; acc[oi][2] = bz; acc[oi][3] = bz;
  }
  for (int c = 0; c < NC; ++c) {
    const float4 x4 = *(const float4*)(xb + (size_t)c * NPOS);
#pragma unroll
    for (int oi = 0; oi < 16; ++oi) {
      float wgt = sW[(16 * wv + oi) * NC + c];
      acc[oi][0] = fmaf(wgt, x4.x, acc[oi][0]);
      acc[oi][1] = fmaf(wgt, x4.y, acc[oi][1]);
      acc[oi][2] = fmaf(wgt, x4.z, acc[oi][2]);
      acc[oi][3] = fmaf(wgt, x4.w, acc[oi][3]);
    }
  }

  if (p < 2) {
    const float qs = (p == 0) ? QSCALE : 1.0f;
    unsigned short* dst = (p == 0 ? qT : kT) + (size_t)b * NPOS * NC;
#pragma unroll
    for (int r = 0; r < 4; ++r) {
      uint4 w0, w1;
      w0.x = pack2(qs * acc[0][r],  qs * acc[1][r]);
      w0.y = pack2(qs * acc[2][r],  qs * acc[3][r]);
      w0.z = pack2(qs * acc[4][r],  qs * acc[5][r]);
      w0.w = pack2(qs * acc[6][r],  qs * acc[7][r]);
      w1.x = pack2(qs * acc[8][r],  qs * acc[9][r]);
      w1.y = pack2(qs * acc[10][r], qs * acc[11][r]);
      w1.z = pack2(qs * acc[12][r], qs * acc[13][r]);
      w1.w = pack2(qs * acc[14][r], qs * acc[15][r]);
      unsigned short* rp = dst + (size_t)(nb + r) * NC + 16 * wv;
      *(uint4*)(rp) = w0;
      *(uint4*)(rp + 8) = w1;
    }
  } else {
#pragma unroll
    for (int oi = 0; oi < 16; ++oi) {
      const int o = 16 * wv + oi;
      float4 v4;
      v4.x = acc[oi][0]; v4.y = acc[oi][1]; v4.z = acc[oi][2]; v4.w = acc[oi][3];
      *(float4*)(vf + ((size_t)b * NC + o) * NPOS + nb) = v4;
      uint2 u2;
      u2.x = pack2(acc[oi][0], acc[oi][1]);
      u2.y = pack2(acc[oi][2], acc[oi][3]);
      *(uint2*)(vb + ((size_t)b * NC + o) * NPOS + nb) = u2;
    }
  }
}

// Stage 2: flash attention partials over an n-chunk, for 64 output columns.
__global__ __launch_bounds__(256, 8) void attn_partial(
    const unsigned short* __restrict__ qT,
    const unsigned short* __restrict__ kT,
    const unsigned short* __restrict__ vb,
    float* __restrict__ pav, float* __restrict__ plsum)
{
  __shared__ unsigned short pT[4][16][72];
  const int b = blockIdx.y, z = blockIdx.z;
  const int m0 = blockIdx.x * 64;
  const int tid = threadIdx.x;
  const int w = tid >> 6, l = tid & 63;
  const int lm = l & 15, g = l >> 4;
  const int m = m0 + 16 * w + lm;

  const unsigned short* kb_p = kT + (size_t)(b * NPOS + m) * NC + 8 * g;
  const bf16x8 kb0 = *(const bf16x8*)(kb_p);
  const bf16x8 kb1 = *(const bf16x8*)(kb_p + 32);

  const unsigned short* qb  = qT + (size_t)b * NPOS * NC;
  const unsigned short* vbb = vb + (size_t)b * NC * NPOS;

  f32x4 acc[4] = {{0,0,0,0},{0,0,0,0},{0,0,0,0},{0,0,0,0}};
  float lsum = 0.f;

  const int nbeg = z * NCHUNK, nend = nbeg + NCHUNK;
  for (int n0 = nbeg; n0 < nend; n0 += 64) {
    f32x4 s[4];
#pragma unroll
    for (int sub = 0; sub < 4; ++sub) {
      const unsigned short* qrow = qb + (size_t)(n0 + 16 * sub + lm) * NC + 8 * g;
      bf16x8 qa0 = *(const bf16x8*)(qrow);
      bf16x8 qa1 = *(const bf16x8*)(qrow + 32);
      f32x4 zz = {0, 0, 0, 0};
      zz = __builtin_amdgcn_mfma_f32_16x16x32_bf16(qa0, kb0, zz, 0, 0, 0);
      zz = __builtin_amdgcn_mfma_f32_16x16x32_bf16(qa1, kb1, zz, 0, 0, 0);
      s[sub] = zz;
    }
#pragma unroll
    for (int sub = 0; sub < 4; ++sub) {
      float p0 = EXP2F(s[sub][0]);
      float p1 = EXP2F(s[sub][1]);
      float p2 = EXP2F(s[sub][2]);
      float p3 = EXP2F(s[sub][3]);
      lsum += (p0 + p1) + (p2 + p3);
      uint2 u;
      u.x = pack2(p0, p1);
      u.y = pack2(p2, p3);
      *(uint2*)&pT[w][lm][16 * sub + 4 * g] = u;
    }
#pragma unroll
    for (int ks = 0; ks < 2; ++ks) {
      bf16x8 pb = *(const bf16x8*)&pT[w][lm][8 * g + 32 * ks];
#pragma unroll
      for (int cs = 0; cs < 4; ++cs) {
        const unsigned short* vrow =
            vbb + (size_t)(16 * cs + lm) * NPOS + n0 + 8 * g + 32 * ks;
        bf16x8 va = *(const bf16x8*)(vrow);
        acc[cs] = __builtin_amdgcn_mfma_f32_16x16x32_bf16(va, pb, acc[cs], 0, 0, 0);
      }
    }
  }

  lsum += __shfl_xor(lsum, 16);
  lsum += __shfl_xor(lsum, 32);
  if (l < 16) plsum[((size_t)(z * NB + b) << 13) + m] = lsum;

  float* po = pav + ((size_t)((z * NB + b) * NC) << 13);
#pragma unroll
  for (int cs = 0; cs < 4; ++cs) {
#pragma unroll
    for (int r = 0; r < 4; ++r) {
      const int c = 16 * cs + 4 * g + r;
      po[((size_t)c << 13) + m] = acc[cs][r];
    }
  }
}

// Stage 3: combine partials, normalize, epilogue.
__global__ __launch_bounds__(256) void reduce_kernel(
    const float* __restrict__ pav, const float* __restrict__ plsum,
    const float* __restrict__ vf, const float* __restrict__ gamma_p,
    float* __restrict__ out)
{
  const size_t base = ((size_t)blockIdx.x * 256 + threadIdx.x) * 4;
  const int m = (int)(base & (NPOS - 1));
  const int bc = (int)(base >> 13);       // b*64 + c
  const int b = bc >> 6;

  float4 s = {0, 0, 0, 0};
  float4 L = {0, 0, 0, 0};
#pragma unroll
  for (int z = 0; z < NSPLIT; ++z) {
    const float4 a = *(const float4*)(pav + (((size_t)(z * NB * NC + bc)) << 13) + m);
    s.x += a.x; s.y += a.y; s.z += a.z; s.w += a.w;
    const float4 q = *(const float4*)(plsum + (((size_t)(z * NB + b)) << 13) + m);
    L.x += q.x; L.y += q.y; L.z += q.z; L.w += q.w;
  }
  const float gmv = gamma_p[0];
  const float4 v4 = *(const float4*)(vf + base);
  float4 o;
  o.x = gmv * s.x / L.x + v4.x;
  o.y = gmv * s.y / L.y + v4.y;
  o.z = gmv * s.z / L.z + v4.z;
  o.w = gmv * s.w / L.w + v4.w;
  *(float4*)(out + base) = o;
}

extern "C" void kernel_launch(void* const* d_in, const int* in_sizes, int n_in,
                              void* d_out, int out_size, void* d_ws, size_t ws_size,
                              hipStream_t stream) {
  const float* xq = (const float*)d_in[0];
  const float* xk = (const float*)d_in[1];
  const float* xv = (const float*)d_in[2];
  const float* Wq = (const float*)d_in[3];
  const float* bq = (const float*)d_in[4];
  const float* Wk = (const float*)d_in[5];
  const float* bk = (const float*)d_in[6];
  const float* Wv = (const float*)d_in[7];
  const float* bv = (const float*)d_in[8];
  const float* gm = (const float*)d_in[9];
  float* out = (float*)d_out;

  // ws: qT(4MB) | kT(4MB) | v_bf16(4MB) | v_f32(8MB) | pav(32MB) | plsum(0.5MB)
  unsigned short* qT   = (unsigned short*)d_ws;
  unsigned short* kT   = qT + (size_t)NB * NPOS * NC;
  unsigned short* vbuf = kT + (size_t)NB * NPOS * NC;
  float* vf    = (float*)(vbuf + (size_t)NB * NPOS * NC);
  float* pav   = vf + (size_t)NB * NC * NPOS;
  float* plsum = pav + (size_t)NSPLIT * NB * NC * NPOS;

  hipLaunchKernelGGL(proj_kernel, dim3(32, 4, 3), dim3(256), 0, stream,
                     xq, xk, xv, Wq, bq, Wk, bk, Wv, bv, qT, kT, vbuf, vf);
  hipLaunchKernelGGL(attn_partial, dim3(128, 4, NSPLIT), dim3(256), 0, stream,
                     qT, kT, vbuf, pav, plsum);
  hipLaunchKernelGGL(reduce_kernel, dim3(2048), dim3(256), 0, stream,
                     pav, plsum, vf, gm, out);
}

// Round 3
// 131.617 us; speedup vs baseline: 3.7148x; 3.7148x over previous
//
#include <hip/hip_runtime.h>

#define NPOS 8192
#define NC 64
#define NB 4
#define NSPLIT 2
#define NCHUNK (NPOS / NSPLIT)
#define ITERS (NCHUNK / 64)
// q pre-scaled by (1/128)*log2(e) so softmax weight = exp2(mfma output)
#define QSCALE 0.01127105500167846f

typedef __bf16 bf16x8 __attribute__((ext_vector_type(8)));
typedef float f32x4 __attribute__((ext_vector_type(4)));

#define EXP2F(x) __builtin_amdgcn_exp2f(x)

static __device__ __forceinline__ unsigned f2bf_u(float x) {
  unsigned u = __float_as_uint(x);
  return (u + 0x7FFFu + ((u >> 16) & 1u)) >> 16;
}
static __device__ __forceinline__ unsigned pack2(float a, float b) {
  return f2bf_u(a) | (f2bf_u(b) << 16);
}

static __device__ __forceinline__ void gload_lds16(const void* gsrc, void* lds_base) {
  __builtin_amdgcn_global_load_lds(
      (const __attribute__((address_space(1))) unsigned int*)gsrc,
      (__attribute__((address_space(3))) unsigned int*)lds_base, 16, 0, 0);
}

// Stage 1: 1x1 conv projections. q,k -> [B][N][C] bf16 (position-major),
// v -> [B][C][N] bf16 + fp32. q additionally scaled by QSCALE.
__global__ __launch_bounds__(256) void proj_kernel(
    const float* __restrict__ xq, const float* __restrict__ xk, const float* __restrict__ xv,
    const float* __restrict__ Wq, const float* __restrict__ bq,
    const float* __restrict__ Wk, const float* __restrict__ bk,
    const float* __restrict__ Wv, const float* __restrict__ bv,
    unsigned short* __restrict__ qT, unsigned short* __restrict__ kT,
    unsigned short* __restrict__ vb, float* __restrict__ vf)
{
  __shared__ float sW[NC * NC];
  __shared__ float sB[NC];
  const int p = blockIdx.z, b = blockIdx.y;
  const int n0 = blockIdx.x * 256;
  const int tid = threadIdx.x;
  const int wv = tid >> 6, l = tid & 63;

  const float* x    = p == 0 ? xq : (p == 1 ? xk : xv);
  const float* W    = p == 0 ? Wq : (p == 1 ? Wk : Wv);
  const float* bias = p == 0 ? bq : (p == 1 ? bk : bv);

  for (int i = tid; i < NC * NC; i += 256) sW[i] = W[i];
  if (tid < NC) sB[tid] = bias[tid];
  __syncthreads();

  const int nb = n0 + 4 * l;
  const float* xb = x + (size_t)b * NC * NPOS + nb;

  float acc[16][4];
#pragma unroll
  for (int oi = 0; oi < 16; ++oi) {
    float bz = sB[16 * wv + oi];
    acc[oi][0] = bz; acc[oi][1] = bz; acc[oi][2] = bz; acc[oi][3] = bz;
  }
  for (int c = 0; c < NC; ++c) {
    const float4 x4 = *(const float4*)(xb + (size_t)c * NPOS);
#pragma unroll
    for (int oi = 0; oi < 16; ++oi) {
      float wgt = sW[(16 * wv + oi) * NC + c];
      acc[oi][0] = fmaf(wgt, x4.x, acc[oi][0]);
      acc[oi][1] = fmaf(wgt, x4.y, acc[oi][1]);
      acc[oi][2] = fmaf(wgt, x4.z, acc[oi][2]);
      acc[oi][3] = fmaf(wgt, x4.w, acc[oi][3]);
    }
  }

  if (p < 2) {
    const float qs = (p == 0) ? QSCALE : 1.0f;
    unsigned short* dst = (p == 0 ? qT : kT) + (size_t)b * NPOS * NC;
#pragma unroll
    for (int r = 0; r < 4; ++r) {
      uint4 w0, w1;
      w0.x = pack2(qs * acc[0][r],  qs * acc[1][r]);
      w0.y = pack2(qs * acc[2][r],  qs * acc[3][r]);
      w0.z = pack2(qs * acc[4][r],  qs * acc[5][r]);
      w0.w = pack2(qs * acc[6][r],  qs * acc[7][r]);
      w1.x = pack2(qs * acc[8][r],  qs * acc[9][r]);
      w1.y = pack2(qs * acc[10][r], qs * acc[11][r]);
      w1.z = pack2(qs * acc[12][r], qs * acc[13][r]);
      w1.w = pack2(qs * acc[14][r], qs * acc[15][r]);
      unsigned short* rp = dst + (size_t)(nb + r) * NC + 16 * wv;
      *(uint4*)(rp) = w0;
      *(uint4*)(rp + 8) = w1;
    }
  } else {
#pragma unroll
    for (int oi = 0; oi < 16; ++oi) {
      const int o = 16 * wv + oi;
      float4 v4;
      v4.x = acc[oi][0]; v4.y = acc[oi][1]; v4.z = acc[oi][2]; v4.w = acc[oi][3];
      *(float4*)(vf + ((size_t)b * NC + o) * NPOS + nb) = v4;
      uint2 u2;
      u2.x = pack2(acc[oi][0], acc[oi][1]);
      u2.y = pack2(acc[oi][2], acc[oi][3]);
      *(uint2*)(vb + ((size_t)b * NC + o) * NPOS + nb) = u2;
    }
  }
}

// Stage 2: flash attention partials. Block = 512 threads (8 waves), 128 cols.
// q-tile [64n x 64c] and v-tile [64c x 64n] staged in swizzled dbuf LDS.
__global__ __launch_bounds__(512) void attn_partial(
    const unsigned short* __restrict__ qT,
    const unsigned short* __restrict__ kT,
    const unsigned short* __restrict__ vb,
    float* __restrict__ pav, float* __restrict__ plsum)
{
  __shared__ unsigned short qs_[2][64 * 64];   // 8KB each, XOR-swizzled rows
  __shared__ unsigned short vs_[2][64 * 64];
  __shared__ unsigned short pT[8][16][72];

  const int b = blockIdx.y, z = blockIdx.z;
  const int m0 = blockIdx.x * 128;
  const int tid = threadIdx.x;
  const int w = tid >> 6, l = tid & 63;
  const int lm = l & 15, g = l >> 4;
  const int m = m0 + 16 * w + lm;

  const unsigned short* kb_p = kT + (size_t)(b * NPOS + m) * NC + 8 * g;
  const bf16x8 kb0 = *(const bf16x8*)(kb_p);
  const bf16x8 kb1 = *(const bf16x8*)(kb_p + 32);

  const char* qb  = (const char*)(qT + (size_t)b * NPOS * NC);
  const char* vbb = (const char*)(vb + (size_t)b * NC * NPOS);

  // staging geometry: thread t writes 16B at LDS byte t*16 = (row=t>>3, swz col (t&7)*16)
  const int srow = tid >> 3;
  const int slc  = ((tid & 7) * 16) ^ ((srow & 7) << 4);  // logical byte col
  const char* qsrc0 = qb + (size_t)srow * 128 + slc;        // + n0*128
  const char* vsrc0 = vbb + (size_t)srow * (NPOS * 2) + slc;  // + n0*2
  const int ldsoff = w * 512;  // shorts; wave-uniform base for global_load_lds

  f32x4 acc[4] = {{0,0,0,0},{0,0,0,0},{0,0,0,0},{0,0,0,0}};
  float lsum = 0.f;

  const int nbeg = z * NCHUNK;

  // prologue: stage buffer 0
  gload_lds16(qsrc0 + (size_t)nbeg * 128, &qs_[0][ldsoff]);
  gload_lds16(vsrc0 + (size_t)nbeg * 2,   &vs_[0][ldsoff]);
  __syncthreads();

  const int swz = (lm & 7) << 4;  // read-side swizzle (row low bits == lm low bits)

  int cur = 0;
  for (int t = 0; t < ITERS; ++t) {
    const int n0 = nbeg + 64 * t;
    if (t + 1 < ITERS) {
      gload_lds16(qsrc0 + (size_t)(n0 + 64) * 128, &qs_[cur ^ 1][ldsoff]);
      gload_lds16(vsrc0 + (size_t)(n0 + 64) * 2,   &vs_[cur ^ 1][ldsoff]);
    }
    const unsigned short* qt = qs_[cur];
    const unsigned short* vt = vs_[cur];

    // QK^T: S'[n][m], 4 n-subtiles of 16, K-dim = 64 channels
    f32x4 s[4];
#pragma unroll
    for (int sub = 0; sub < 4; ++sub) {
      const int nl = 16 * sub + lm;
      bf16x8 qa0 = *(const bf16x8*)(qt + nl * 64 + (((16 * g) ^ swz) >> 1));
      bf16x8 qa1 = *(const bf16x8*)(qt + nl * 64 + (((64 + 16 * g) ^ swz) >> 1));
      f32x4 zz = {0, 0, 0, 0};
      zz = __builtin_amdgcn_mfma_f32_16x16x32_bf16(qa0, kb0, zz, 0, 0, 0);
      zz = __builtin_amdgcn_mfma_f32_16x16x32_bf16(qa1, kb1, zz, 0, 0, 0);
      s[sub] = zz;
    }
    // softmax weights (no max-subtraction; scores tiny)
#pragma unroll
    for (int sub = 0; sub < 4; ++sub) {
      float p0 = EXP2F(s[sub][0]);
      float p1 = EXP2F(s[sub][1]);
      float p2 = EXP2F(s[sub][2]);
      float p3 = EXP2F(s[sub][3]);
      lsum += (p0 + p1) + (p2 + p3);
      uint2 u;
      u.x = pack2(p0, p1);
      u.y = pack2(p2, p3);
      *(uint2*)&pT[w][lm][16 * sub + 4 * g] = u;
    }
    // PV: av[c][m] += V[c][n] * P[n][m]
#pragma unroll
    for (int ks = 0; ks < 2; ++ks) {
      bf16x8 pb = *(const bf16x8*)&pT[w][lm][8 * g + 32 * ks];
#pragma unroll
      for (int cs = 0; cs < 4; ++cs) {
        const int vr = 16 * cs + lm;
        bf16x8 va = *(const bf16x8*)(vt + vr * 64 + (((16 * g + 64 * ks) ^ swz) >> 1));
        acc[cs] = __builtin_amdgcn_mfma_f32_16x16x32_bf16(va, pb, acc[cs], 0, 0, 0);
      }
    }
    __syncthreads();  // compiler drains vmcnt+lgkm before barrier
    cur ^= 1;
  }

  lsum += __shfl_xor(lsum, 16);
  lsum += __shfl_xor(lsum, 32);
  if (l < 16) plsum[((size_t)(z * NB + b) << 13) + m] = lsum;

  float* po = pav + ((size_t)((z * NB + b) * NC) << 13);
#pragma unroll
  for (int cs = 0; cs < 4; ++cs) {
#pragma unroll
    for (int r = 0; r < 4; ++r) {
      const int c = 16 * cs + 4 * g + r;
      po[((size_t)c << 13) + m] = acc[cs][r];
    }
  }
}

// Stage 3: combine partials, normalize, epilogue.
__global__ __launch_bounds__(256) void reduce_kernel(
    const float* __restrict__ pav, const float* __restrict__ plsum,
    const float* __restrict__ vf, const float* __restrict__ gamma_p,
    float* __restrict__ out)
{
  const size_t base = ((size_t)blockIdx.x * 256 + threadIdx.x) * 4;
  const int m = (int)(base & (NPOS - 1));
  const int bc = (int)(base >> 13);       // b*64 + c
  const int b = bc >> 6;

  float4 s = {0, 0, 0, 0};
  float4 L = {0, 0, 0, 0};
#pragma unroll
  for (int zz = 0; zz < NSPLIT; ++zz) {
    const float4 a = *(const float4*)(pav + (((size_t)(zz * NB * NC + bc)) << 13) + m);
    s.x += a.x; s.y += a.y; s.z += a.z; s.w += a.w;
    const float4 q = *(const float4*)(plsum + (((size_t)(zz * NB + b)) << 13) + m);
    L.x += q.x; L.y += q.y; L.z += q.z; L.w += q.w;
  }
  const float gmv = gamma_p[0];
  const float4 v4 = *(const float4*)(vf + base);
  float4 o;
  o.x = gmv * s.x / L.x + v4.x;
  o.y = gmv * s.y / L.y + v4.y;
  o.z = gmv * s.z / L.z + v4.z;
  o.w = gmv * s.w / L.w + v4.w;
  *(float4*)(out + base) = o;
}

extern "C" void kernel_launch(void* const* d_in, const int* in_sizes, int n_in,
                              void* d_out, int out_size, void* d_ws, size_t ws_size,
                              hipStream_t stream) {
  const float* xq = (const float*)d_in[0];
  const float* xk = (const float*)d_in[1];
  const float* xv = (const float*)d_in[2];
  const float* Wq = (const float*)d_in[3];
  const float* bq = (const float*)d_in[4];
  const float* Wk = (const float*)d_in[5];
  const float* bk = (const float*)d_in[6];
  const float* Wv = (const float*)d_in[7];
  const float* bv = (const float*)d_in[8];
  const float* gm = (const float*)d_in[9];
  float* out = (float*)d_out;

  // ws: qT(4MB) | kT(4MB) | v_bf16(4MB) | v_f32(8MB) | pav(16MB) | plsum(256KB)
  unsigned short* qT   = (unsigned short*)d_ws;
  unsigned short* kT   = qT + (size_t)NB * NPOS * NC;
  unsigned short* vbuf = kT + (size_t)NB * NPOS * NC;
  float* vf    = (float*)(vbuf + (size_t)NB * NPOS * NC);
  float* pav   = vf + (size_t)NB * NC * NPOS;
  float* plsum = pav + (size_t)NSPLIT * NB * NC * NPOS;

  hipLaunchKernelGGL(proj_kernel, dim3(32, 4, 3), dim3(256), 0, stream,
                     xq, xk, xv, Wq, bq, Wk, bk, Wv, bv, qT, kT, vbuf, vf);
  hipLaunchKernelGGL(attn_partial, dim3(NPOS / 128, NB, NSPLIT), dim3(512), 0, stream,
                     qT, kT, vbuf, pav, plsum);
  hipLaunchKernelGGL(reduce_kernel, dim3(2048), dim3(256), 0, stream,
                     pav, plsum, vf, gm, out);
}

// Round 4
// 121.010 us; speedup vs baseline: 4.0404x; 1.0876x over previous
//
#include <hip/hip_runtime.h>

#define NPOS 8192
#define NC 64
#define NB 4
#define NSPLIT 3
#define NCHUNK 2752  // 43*64; last chunk is 2688 (42*64)
// q pre-scaled by (1/128)*log2(e) so softmax weight = exp2(mfma output)
#define QSCALE 0.01127105500167846f

typedef __bf16 bf16x8 __attribute__((ext_vector_type(8)));
typedef __bf16 bf16x4 __attribute__((ext_vector_type(4)));
typedef float f32x4 __attribute__((ext_vector_type(4)));

#define EXP2F(x) __builtin_amdgcn_exp2f(x)

static __device__ __forceinline__ unsigned f2bf_u(float x) {
  unsigned u = __float_as_uint(x);
  return (u + 0x7FFFu + ((u >> 16) & 1u)) >> 16;
}
static __device__ __forceinline__ unsigned pack2(float a, float b) {
  return f2bf_u(a) | (f2bf_u(b) << 16);
}

static __device__ __forceinline__ void gload_lds16(const void* gsrc, void* lds_base) {
  __builtin_amdgcn_global_load_lds(
      (const __attribute__((address_space(1))) unsigned int*)gsrc,
      (__attribute__((address_space(3))) unsigned int*)lds_base, 16, 0, 0);
}

// Stage 1: 1x1 conv projections. q,k -> [B][N][C] bf16 (position-major),
// v -> [B][C][N] bf16 + fp32. q additionally scaled by QSCALE.
__global__ __launch_bounds__(256) void proj_kernel(
    const float* __restrict__ xq, const float* __restrict__ xk, const float* __restrict__ xv,
    const float* __restrict__ Wq, const float* __restrict__ bq,
    const float* __restrict__ Wk, const float* __restrict__ bk,
    const float* __restrict__ Wv, const float* __restrict__ bv,
    unsigned short* __restrict__ qT, unsigned short* __restrict__ kT,
    unsigned short* __restrict__ vb, float* __restrict__ vf)
{
  __shared__ float sW[NC * NC];
  __shared__ float sB[NC];
  const int p = blockIdx.z, b = blockIdx.y;
  const int n0 = blockIdx.x * 256;
  const int tid = threadIdx.x;
  const int wv = tid >> 6, l = tid & 63;

  const float* x    = p == 0 ? xq : (p == 1 ? xk : xv);
  const float* W    = p == 0 ? Wq : (p == 1 ? Wk : Wv);
  const float* bias = p == 0 ? bq : (p == 1 ? bk : bv);

  for (int i = tid; i < NC * NC; i += 256) sW[i] = W[i];
  if (tid < NC) sB[tid] = bias[tid];
  __syncthreads();

  const int nb = n0 + 4 * l;
  const float* xb = x + (size_t)b * NC * NPOS + nb;

  float acc[16][4];
#pragma unroll
  for (int oi = 0; oi < 16; ++oi) {
    float bz = sB[16 * wv + oi];
    acc[oi][0] = bz; acc[oi][1] = bz; acc[oi][2] = bz; acc[oi][3] = bz;
  }
  for (int c = 0; c < NC; ++c) {
    const float4 x4 = *(const float4*)(xb + (size_t)c * NPOS);
#pragma unroll
    for (int oi = 0; oi < 16; ++oi) {
      float wgt = sW[(16 * wv + oi) * NC + c];
      acc[oi][0] = fmaf(wgt, x4.x, acc[oi][0]);
      acc[oi][1] = fmaf(wgt, x4.y, acc[oi][1]);
      acc[oi][2] = fmaf(wgt, x4.z, acc[oi][2]);
      acc[oi][3] = fmaf(wgt, x4.w, acc[oi][3]);
    }
  }

  if (p < 2) {
    const float qs = (p == 0) ? QSCALE : 1.0f;
    unsigned short* dst = (p == 0 ? qT : kT) + (size_t)b * NPOS * NC;
#pragma unroll
    for (int r = 0; r < 4; ++r) {
      uint4 w0, w1;
      w0.x = pack2(qs * acc[0][r],  qs * acc[1][r]);
      w0.y = pack2(qs * acc[2][r],  qs * acc[3][r]);
      w0.z = pack2(qs * acc[4][r],  qs * acc[5][r]);
      w0.w = pack2(qs * acc[6][r],  qs * acc[7][r]);
      w1.x = pack2(qs * acc[8][r],  qs * acc[9][r]);
      w1.y = pack2(qs * acc[10][r], qs * acc[11][r]);
      w1.z = pack2(qs * acc[12][r], qs * acc[13][r]);
      w1.w = pack2(qs * acc[14][r], qs * acc[15][r]);
      unsigned short* rp = dst + (size_t)(nb + r) * NC + 16 * wv;
      *(uint4*)(rp) = w0;
      *(uint4*)(rp + 8) = w1;
    }
  } else {
#pragma unroll
    for (int oi = 0; oi < 16; ++oi) {
      const int o = 16 * wv + oi;
      float4 v4;
      v4.x = acc[oi][0]; v4.y = acc[oi][1]; v4.z = acc[oi][2]; v4.w = acc[oi][3];
      *(float4*)(vf + ((size_t)b * NC + o) * NPOS + nb) = v4;
      uint2 u2;
      u2.x = pack2(acc[oi][0], acc[oi][1]);
      u2.y = pack2(acc[oi][2], acc[oi][3]);
      *(uint2*)(vb + ((size_t)b * NC + o) * NPOS + nb) = u2;
    }
  }
}

// Stage 2: flash attention partials. Block = 512 threads (8 waves), 128 cols.
// q-tile [64n x 64c] and v-tile [64c x 64n] staged in swizzled dbuf LDS.
__global__ __launch_bounds__(512) void attn_partial(
    const unsigned short* __restrict__ qT,
    const unsigned short* __restrict__ kT,
    const unsigned short* __restrict__ vb,
    float* __restrict__ pav, float* __restrict__ plsum)
{
  __shared__ unsigned short qs_[2][64 * 64];   // 8KB each, XOR-swizzled rows
  __shared__ unsigned short vs_[2][64 * 64];
  __shared__ unsigned short pT[8][16][72];     // stride 144B = 36 banks -> 2-way max

  const int b = blockIdx.y, z = blockIdx.z;
  const int m0 = blockIdx.x * 128;
  const int tid = threadIdx.x;
  const int w = tid >> 6, l = tid & 63;
  const int lm = l & 15, g = l >> 4;
  const int m = m0 + 16 * w + lm;

  const unsigned short* kb_p = kT + (size_t)(b * NPOS + m) * NC + 8 * g;
  const bf16x8 kb0 = *(const bf16x8*)(kb_p);
  const bf16x8 kb1 = *(const bf16x8*)(kb_p + 32);

  const char* qb  = (const char*)(qT + (size_t)b * NPOS * NC);
  const char* vbb = (const char*)(vb + (size_t)b * NC * NPOS);

  // staging geometry: thread t writes 16B at LDS byte t*16 = (row=t>>3, swz col (t&7)*16)
  const int srow = tid >> 3;
  const int slc  = ((tid & 7) * 16) ^ ((srow & 7) << 4);  // logical byte col
  const char* qsrc0 = qb + (size_t)srow * 128 + slc;          // + n0*128
  const char* vsrc0 = vbb + (size_t)srow * (NPOS * 2) + slc;  // + n0*2
  const int ldsoff = w * 512;  // shorts; wave-uniform base for global_load_lds

  f32x4 acc[4] = {{0,0,0,0},{0,0,0,0},{0,0,0,0},{0,0,0,0}};
  float lsum = 0.f;

  const int nbeg = z * NCHUNK;
  const int nend = (nbeg + NCHUNK < NPOS) ? nbeg + NCHUNK : NPOS;
  const int iters = (nend - nbeg) >> 6;

  // prologue: stage buffer 0
  gload_lds16(qsrc0 + (size_t)nbeg * 128, &qs_[0][ldsoff]);
  gload_lds16(vsrc0 + (size_t)nbeg * 2,   &vs_[0][ldsoff]);
  __syncthreads();

  const int swz = (lm & 7) << 4;  // read-side swizzle (row low bits == lm low bits)

  int cur = 0;
  for (int t = 0; t < iters; ++t) {
    const int n0 = nbeg + 64 * t;
    if (t + 1 < iters) {
      gload_lds16(qsrc0 + (size_t)(n0 + 64) * 128, &qs_[cur ^ 1][ldsoff]);
      gload_lds16(vsrc0 + (size_t)(n0 + 64) * 2,   &vs_[cur ^ 1][ldsoff]);
    }
    const unsigned short* qt = qs_[cur];
    const unsigned short* vt = vs_[cur];

    // QK^T: S'[n][m], 4 n-subtiles of 16, K-dim = 64 channels
    f32x4 s[4];
#pragma unroll
    for (int sub = 0; sub < 4; ++sub) {
      const int nl = 16 * sub + lm;
      bf16x8 qa0 = *(const bf16x8*)(qt + nl * 64 + (((16 * g) ^ swz) >> 1));
      bf16x8 qa1 = *(const bf16x8*)(qt + nl * 64 + (((64 + 16 * g) ^ swz) >> 1));
      f32x4 zz = {0, 0, 0, 0};
      zz = __builtin_amdgcn_mfma_f32_16x16x32_bf16(qa0, kb0, zz, 0, 0, 0);
      zz = __builtin_amdgcn_mfma_f32_16x16x32_bf16(qa1, kb1, zz, 0, 0, 0);
      s[sub] = zz;
    }
    // softmax weights (no max-subtraction; scores tiny). Native casts -> cvt_pk.
#pragma unroll
    for (int sub = 0; sub < 4; ++sub) {
      float p0 = EXP2F(s[sub][0]);
      float p1 = EXP2F(s[sub][1]);
      float p2 = EXP2F(s[sub][2]);
      float p3 = EXP2F(s[sub][3]);
      lsum += (p0 + p1) + (p2 + p3);
      bf16x4 pk;
      pk[0] = (__bf16)p0; pk[1] = (__bf16)p1;
      pk[2] = (__bf16)p2; pk[3] = (__bf16)p3;
      *(bf16x4*)&pT[w][lm][16 * sub + 4 * g] = pk;
    }
    // PV: av[c][m] += V[c][n] * P[n][m]
#pragma unroll
    for (int ks = 0; ks < 2; ++ks) {
      bf16x8 pb = *(const bf16x8*)&pT[w][lm][8 * g + 32 * ks];
#pragma unroll
      for (int cs = 0; cs < 4; ++cs) {
        const int vr = 16 * cs + lm;
        bf16x8 va = *(const bf16x8*)(vt + vr * 64 + (((16 * g + 64 * ks) ^ swz) >> 1));
        acc[cs] = __builtin_amdgcn_mfma_f32_16x16x32_bf16(va, pb, acc[cs], 0, 0, 0);
      }
    }
    __syncthreads();  // drains vmcnt+lgkm before barrier
    cur ^= 1;
  }

  lsum += __shfl_xor(lsum, 16);
  lsum += __shfl_xor(lsum, 32);
  if (l < 16) plsum[((size_t)(z * NB + b) << 13) + m] = lsum;

  float* po = pav + ((size_t)((z * NB + b) * NC) << 13);
#pragma unroll
  for (int cs = 0; cs < 4; ++cs) {
#pragma unroll
    for (int r = 0; r < 4; ++r) {
      const int c = 16 * cs + 4 * g + r;
      po[((size_t)c << 13) + m] = acc[cs][r];
    }
  }
}

// Stage 3: combine partials, normalize, epilogue.
__global__ __launch_bounds__(256) void reduce_kernel(
    const float* __restrict__ pav, const float* __restrict__ plsum,
    const float* __restrict__ vf, const float* __restrict__ gamma_p,
    float* __restrict__ out)
{
  const size_t base = ((size_t)blockIdx.x * 256 + threadIdx.x) * 4;
  const int m = (int)(base & (NPOS - 1));
  const int bc = (int)(base >> 13);       // b*64 + c
  const int b = bc >> 6;

  float4 s = {0, 0, 0, 0};
  float4 L = {0, 0, 0, 0};
#pragma unroll
  for (int zz = 0; zz < NSPLIT; ++zz) {
    const float4 a = *(const float4*)(pav + (((size_t)(zz * NB * NC + bc)) << 13) + m);
    s.x += a.x; s.y += a.y; s.z += a.z; s.w += a.w;
    const float4 q = *(const float4*)(plsum + (((size_t)(zz * NB + b)) << 13) + m);
    L.x += q.x; L.y += q.y; L.z += q.z; L.w += q.w;
  }
  const float gmv = gamma_p[0];
  const float4 v4 = *(const float4*)(vf + base);
  float4 o;
  o.x = gmv * s.x / L.x + v4.x;
  o.y = gmv * s.y / L.y + v4.y;
  o.z = gmv * s.z / L.z + v4.z;
  o.w = gmv * s.w / L.w + v4.w;
  *(float4*)(out + base) = o;
}

extern "C" void kernel_launch(void* const* d_in, const int* in_sizes, int n_in,
                              void* d_out, int out_size, void* d_ws, size_t ws_size,
                              hipStream_t stream) {
  const float* xq = (const float*)d_in[0];
  const float* xk = (const float*)d_in[1];
  const float* xv = (const float*)d_in[2];
  const float* Wq = (const float*)d_in[3];
  const float* bq = (const float*)d_in[4];
  const float* Wk = (const float*)d_in[5];
  const float* bk = (const float*)d_in[6];
  const float* Wv = (const float*)d_in[7];
  const float* bv = (const float*)d_in[8];
  const float* gm = (const float*)d_in[9];
  float* out = (float*)d_out;

  // ws: qT(4MB) | kT(4MB) | v_bf16(4MB) | v_f32(8MB) | pav(24MB) | plsum(384KB)
  unsigned short* qT   = (unsigned short*)d_ws;
  unsigned short* kT   = qT + (size_t)NB * NPOS * NC;
  unsigned short* vbuf = kT + (size_t)NB * NPOS * NC;
  float* vf    = (float*)(vbuf + (size_t)NB * NPOS * NC);
  float* pav   = vf + (size_t)NB * NC * NPOS;
  float* plsum = pav + (size_t)NSPLIT * NB * NC * NPOS;

  hipLaunchKernelGGL(proj_kernel, dim3(32, 4, 3), dim3(256), 0, stream,
                     xq, xk, xv, Wq, bq, Wk, bk, Wv, bv, qT, kT, vbuf, vf);
  hipLaunchKernelGGL(attn_partial, dim3(NPOS / 128, NB, NSPLIT), dim3(512), 0, stream,
                     qT, kT, vbuf, pav, plsum);
  hipLaunchKernelGGL(reduce_kernel, dim3(2048), dim3(256), 0, stream,
                     pav, plsum, vf, gm, out);
}

// Round 5
// 115.201 us; speedup vs baseline: 4.2442x; 1.0504x over previous
//
#include <hip/hip_runtime.h>

#define NPOS 8192
#define NC 64
#define NB 4
#define NSPLIT 3
#define NCHUNK 2752  // 43*64; last chunk is 2688 (42*64)
// q pre-scaled by (1/128)*log2(e) so softmax weight = exp2(mfma output)
#define QSCALE 0.01127105500167846f

typedef __bf16 bf16x8 __attribute__((ext_vector_type(8)));
typedef __bf16 bf16x4 __attribute__((ext_vector_type(4)));
typedef float f32x4 __attribute__((ext_vector_type(4)));

#define EXP2F(x) __builtin_amdgcn_exp2f(x)

static __device__ __forceinline__ unsigned f2bf_u(float x) {
  unsigned u = __float_as_uint(x);
  return (u + 0x7FFFu + ((u >> 16) & 1u)) >> 16;
}
static __device__ __forceinline__ unsigned pack2(float a, float b) {
  return f2bf_u(a) | (f2bf_u(b) << 16);
}

static __device__ __forceinline__ void gload_lds16(const void* gsrc, void* lds_base) {
  __builtin_amdgcn_global_load_lds(
      (const __attribute__((address_space(1))) unsigned int*)gsrc,
      (__attribute__((address_space(3))) unsigned int*)lds_base, 16, 0, 0);
}

// Stage 1: 1x1 conv projections. q,k -> [B][N][C] bf16 (position-major),
// v -> [B][C][N] bf16 + fp32. q additionally scaled by QSCALE.
// Each block: 128 positions; thread (wv,l) does 16 out-channels x 2 positions.
__global__ __launch_bounds__(256) void proj_kernel(
    const float* __restrict__ xq, const float* __restrict__ xk, const float* __restrict__ xv,
    const float* __restrict__ Wq, const float* __restrict__ bq,
    const float* __restrict__ Wk, const float* __restrict__ bk,
    const float* __restrict__ Wv, const float* __restrict__ bv,
    unsigned short* __restrict__ qT, unsigned short* __restrict__ kT,
    unsigned short* __restrict__ vb, float* __restrict__ vf)
{
  __shared__ float sW[NC * NC];
  __shared__ float sB[NC];
  const int p = blockIdx.z, b = blockIdx.y;
  const int n0 = blockIdx.x * 128;
  const int tid = threadIdx.x;
  const int wv = tid >> 6, l = tid & 63;

  const float* x    = p == 0 ? xq : (p == 1 ? xk : xv);
  const float* W    = p == 0 ? Wq : (p == 1 ? Wk : Wv);
  const float* bias = p == 0 ? bq : (p == 1 ? bk : bv);

  for (int i = tid; i < NC * NC; i += 256) sW[i] = W[i];
  if (tid < NC) sB[tid] = bias[tid];
  __syncthreads();

  const int nb = n0 + 2 * l;
  const float* xb = x + (size_t)b * NC * NPOS + nb;

  float acc[16][2];
#pragma unroll
  for (int oi = 0; oi < 16; ++oi) {
    float bz = sB[16 * wv + oi];
    acc[oi][0] = bz; acc[oi][1] = bz;
  }
  for (int c = 0; c < NC; ++c) {
    const float2 x2 = *(const float2*)(xb + (size_t)c * NPOS);
#pragma unroll
    for (int oi = 0; oi < 16; ++oi) {
      float wgt = sW[(16 * wv + oi) * NC + c];
      acc[oi][0] = fmaf(wgt, x2.x, acc[oi][0]);
      acc[oi][1] = fmaf(wgt, x2.y, acc[oi][1]);
    }
  }

  if (p < 2) {
    const float qs = (p == 0) ? QSCALE : 1.0f;
    unsigned short* dst = (p == 0 ? qT : kT) + (size_t)b * NPOS * NC;
#pragma unroll
    for (int r = 0; r < 2; ++r) {
      uint4 w0, w1;
      w0.x = pack2(qs * acc[0][r],  qs * acc[1][r]);
      w0.y = pack2(qs * acc[2][r],  qs * acc[3][r]);
      w0.z = pack2(qs * acc[4][r],  qs * acc[5][r]);
      w0.w = pack2(qs * acc[6][r],  qs * acc[7][r]);
      w1.x = pack2(qs * acc[8][r],  qs * acc[9][r]);
      w1.y = pack2(qs * acc[10][r], qs * acc[11][r]);
      w1.z = pack2(qs * acc[12][r], qs * acc[13][r]);
      w1.w = pack2(qs * acc[14][r], qs * acc[15][r]);
      unsigned short* rp = dst + (size_t)(nb + r) * NC + 16 * wv;
      *(uint4*)(rp) = w0;
      *(uint4*)(rp + 8) = w1;
    }
  } else {
#pragma unroll
    for (int oi = 0; oi < 16; ++oi) {
      const int o = 16 * wv + oi;
      float2 v2;
      v2.x = acc[oi][0]; v2.y = acc[oi][1];
      *(float2*)(vf + ((size_t)b * NC + o) * NPOS + nb) = v2;
      *(unsigned*)(vb + ((size_t)b * NC + o) * NPOS + nb) = pack2(acc[oi][0], acc[oi][1]);
    }
  }
}

// Stage 2: flash attention partials. Block = 512 threads (8 waves), 128 cols.
// 2-buffer LDS staging with counted vmcnt (prefetch survives the barrier).
__global__ __launch_bounds__(512) void attn_partial(
    const unsigned short* __restrict__ qT,
    const unsigned short* __restrict__ kT,
    const unsigned short* __restrict__ vb,
    float* __restrict__ pav, float* __restrict__ plsum)
{
  __shared__ unsigned short qs_[2][64 * 64];   // 8KB each, XOR-swizzled rows
  __shared__ unsigned short vs_[2][64 * 64];
  __shared__ unsigned short pT[8][16][68];     // stride 136B: conflict-free b64 r/w

  const int b = blockIdx.y, z = blockIdx.z;
  const int m0 = blockIdx.x * 128;
  const int tid = threadIdx.x;
  const int w = tid >> 6, l = tid & 63;
  const int lm = l & 15, g = l >> 4;
  const int m = m0 + 16 * w + lm;

  const unsigned short* kb_p = kT + (size_t)(b * NPOS + m) * NC + 8 * g;
  const bf16x8 kb0 = *(const bf16x8*)(kb_p);
  const bf16x8 kb1 = *(const bf16x8*)(kb_p + 32);

  const char* qb  = (const char*)(qT + (size_t)b * NPOS * NC);
  const char* vbb = (const char*)(vb + (size_t)b * NC * NPOS);

  // staging geometry: thread t writes 16B at LDS byte t*16 = (row=t>>3, swz col (t&7)*16)
  const int srow = tid >> 3;
  const int slc  = ((tid & 7) * 16) ^ ((srow & 7) << 4);  // inverse-swizzled src col
  const char* qsrc0 = qb + (size_t)srow * 128 + slc;          // + n0*128
  const char* vsrc0 = vbb + (size_t)srow * (NPOS * 2) + slc;  // + n0*2
  const int ldsoff = w * 512;  // shorts; wave-uniform base for global_load_lds

  f32x4 acc[4] = {{0,0,0,0},{0,0,0,0},{0,0,0,0},{0,0,0,0}};
  float lsum = 0.f;

  const int nbeg = z * NCHUNK;
  const int nend = (nbeg + NCHUNK < NPOS) ? nbeg + NCHUNK : NPOS;
  const int iters = (nend - nbeg) >> 6;

  // prologue: stage buffer 0
  gload_lds16(qsrc0 + (size_t)nbeg * 128, &qs_[0][ldsoff]);
  gload_lds16(vsrc0 + (size_t)nbeg * 2,   &vs_[0][ldsoff]);

  const int swz = (lm & 7) << 4;  // read-side swizzle

  int cur = 0;
  for (int t = 0; t < iters; ++t) {
    const int n0 = nbeg + 64 * t;
    // barrier A: everyone finished reading buf cur^1 (iter t-1) -> safe to overwrite
    __builtin_amdgcn_s_barrier();
    if (t + 1 < iters) {
      gload_lds16(qsrc0 + (size_t)(n0 + 64) * 128, &qs_[cur ^ 1][ldsoff]);
      gload_lds16(vsrc0 + (size_t)(n0 + 64) * 2,   &vs_[cur ^ 1][ldsoff]);
      asm volatile("s_waitcnt vmcnt(2)" ::: "memory");  // stage(t) done; t+1 in flight
    } else {
      asm volatile("s_waitcnt vmcnt(0)" ::: "memory");  // last tile: drain
    }
    // barrier B: all waves' stage(t) complete -> tile readable
    __builtin_amdgcn_s_barrier();
    __builtin_amdgcn_sched_barrier(0);

    const unsigned short* qt = qs_[cur];
    const unsigned short* vt = vs_[cur];

    // QK^T: S'[n][m], 4 n-subtiles of 16, K-dim = 64 channels
    f32x4 s[4];
    __builtin_amdgcn_s_setprio(1);
#pragma unroll
    for (int sub = 0; sub < 4; ++sub) {
      const int nl = 16 * sub + lm;
      bf16x8 qa0 = *(const bf16x8*)(qt + nl * 64 + (((16 * g) ^ swz) >> 1));
      bf16x8 qa1 = *(const bf16x8*)(qt + nl * 64 + (((64 + 16 * g) ^ swz) >> 1));
      f32x4 zz = {0, 0, 0, 0};
      zz = __builtin_amdgcn_mfma_f32_16x16x32_bf16(qa0, kb0, zz, 0, 0, 0);
      zz = __builtin_amdgcn_mfma_f32_16x16x32_bf16(qa1, kb1, zz, 0, 0, 0);
      s[sub] = zz;
    }
    __builtin_amdgcn_s_setprio(0);
    // softmax weights (no max-subtraction; scores tiny). Native casts -> cvt_pk.
#pragma unroll
    for (int sub = 0; sub < 4; ++sub) {
      float p0 = EXP2F(s[sub][0]);
      float p1 = EXP2F(s[sub][1]);
      float p2 = EXP2F(s[sub][2]);
      float p3 = EXP2F(s[sub][3]);
      lsum += (p0 + p1) + (p2 + p3);
      bf16x4 pk;
      pk[0] = (__bf16)p0; pk[1] = (__bf16)p1;
      pk[2] = (__bf16)p2; pk[3] = (__bf16)p3;
      *(bf16x4*)&pT[w][lm][16 * sub + 4 * g] = pk;
    }
    // PV: av[c][m] += V[c][n] * P[n][m]
    __builtin_amdgcn_s_setprio(1);
#pragma unroll
    for (int ks = 0; ks < 2; ++ks) {
      bf16x8 pb = *(const bf16x8*)&pT[w][lm][8 * g + 32 * ks];
#pragma unroll
      for (int cs = 0; cs < 4; ++cs) {
        const int vr = 16 * cs + lm;
        bf16x8 va = *(const bf16x8*)(vt + vr * 64 + (((16 * g + 64 * ks) ^ swz) >> 1));
        acc[cs] = __builtin_amdgcn_mfma_f32_16x16x32_bf16(va, pb, acc[cs], 0, 0, 0);
      }
    }
    __builtin_amdgcn_s_setprio(0);
    cur ^= 1;
  }

  lsum += __shfl_xor(lsum, 16);
  lsum += __shfl_xor(lsum, 32);
  if (l < 16) plsum[((size_t)(z * NB + b) << 13) + m] = lsum;

  float* po = pav + ((size_t)((z * NB + b) * NC) << 13);
#pragma unroll
  for (int cs = 0; cs < 4; ++cs) {
#pragma unroll
    for (int r = 0; r < 4; ++r) {
      const int c = 16 * cs + 4 * g + r;
      po[((size_t)c << 13) + m] = acc[cs][r];
    }
  }
}

// Stage 3: combine partials, normalize, epilogue.
__global__ __launch_bounds__(256) void reduce_kernel(
    const float* __restrict__ pav, const float* __restrict__ plsum,
    const float* __restrict__ vf, const float* __restrict__ gamma_p,
    float* __restrict__ out)
{
  const size_t base = ((size_t)blockIdx.x * 256 + threadIdx.x) * 4;
  const int m = (int)(base & (NPOS - 1));
  const int bc = (int)(base >> 13);       // b*64 + c
  const int b = bc >> 6;

  float4 s = {0, 0, 0, 0};
  float4 L = {0, 0, 0, 0};
#pragma unroll
  for (int zz = 0; zz < NSPLIT; ++zz) {
    const float4 a = *(const float4*)(pav + (((size_t)(zz * NB * NC + bc)) << 13) + m);
    s.x += a.x; s.y += a.y; s.z += a.z; s.w += a.w;
    const float4 q = *(const float4*)(plsum + (((size_t)(zz * NB + b)) << 13) + m);
    L.x += q.x; L.y += q.y; L.z += q.z; L.w += q.w;
  }
  const float gmv = gamma_p[0];
  const float4 v4 = *(const float4*)(vf + base);
  float4 o;
  o.x = gmv * s.x / L.x + v4.x;
  o.y = gmv * s.y / L.y + v4.y;
  o.z = gmv * s.z / L.z + v4.z;
  o.w = gmv * s.w / L.w + v4.w;
  *(float4*)(out + base) = o;
}

extern "C" void kernel_launch(void* const* d_in, const int* in_sizes, int n_in,
                              void* d_out, int out_size, void* d_ws, size_t ws_size,
                              hipStream_t stream) {
  const float* xq = (const float*)d_in[0];
  const float* xk = (const float*)d_in[1];
  const float* xv = (const float*)d_in[2];
  const float* Wq = (const float*)d_in[3];
  const float* bq = (const float*)d_in[4];
  const float* Wk = (const float*)d_in[5];
  const float* bk = (const float*)d_in[6];
  const float* Wv = (const float*)d_in[7];
  const float* bv = (const float*)d_in[8];
  const float* gm = (const float*)d_in[9];
  float* out = (float*)d_out;

  // ws: qT(4MB) | kT(4MB) | v_bf16(4MB) | v_f32(8MB) | pav(24MB) | plsum(384KB)
  unsigned short* qT   = (unsigned short*)d_ws;
  unsigned short* kT   = qT + (size_t)NB * NPOS * NC;
  unsigned short* vbuf = kT + (size_t)NB * NPOS * NC;
  float* vf    = (float*)(vbuf + (size_t)NB * NPOS * NC);
  float* pav   = vf + (size_t)NB * NC * NPOS;
  float* plsum = pav + (size_t)NSPLIT * NB * NC * NPOS;

  hipLaunchKernelGGL(proj_kernel, dim3(64, 4, 3), dim3(256), 0, stream,
                     xq, xk, xv, Wq, bq, Wk, bk, Wv, bv, qT, kT, vbuf, vf);
  hipLaunchKernelGGL(attn_partial, dim3(NPOS / 128, NB, NSPLIT), dim3(512), 0, stream,
                     qT, kT, vbuf, pav, plsum);
  hipLaunchKernelGGL(reduce_kernel, dim3(2048), dim3(256), 0, stream,
                     pav, plsum, vf, gm, out);
}

// Round 6
// 109.202 us; speedup vs baseline: 4.4773x; 1.0549x over previous
//
#include <hip/hip_runtime.h>

#define NPOS 8192
#define NC 64
#define NB 4
#define NSPLIT 4
#define NCHUNK 2048  // 32 tiles of 64, even split, no tail
// q pre-scaled by (1/128)*log2(e) so softmax weight = exp2(mfma output)
#define QSCALE 0.01127105500167846f

typedef __bf16 bf16x8 __attribute__((ext_vector_type(8)));
typedef __bf16 bf16x4 __attribute__((ext_vector_type(4)));
typedef float f32x4 __attribute__((ext_vector_type(4)));

#define EXP2F(x) __builtin_amdgcn_exp2f(x)

static __device__ __forceinline__ unsigned f2bf_u(float x) {
  unsigned u = __float_as_uint(x);
  return (u + 0x7FFFu + ((u >> 16) & 1u)) >> 16;
}
static __device__ __forceinline__ unsigned pack2(float a, float b) {
  return f2bf_u(a) | (f2bf_u(b) << 16);
}

static __device__ __forceinline__ void gload_lds16(const void* gsrc, void* lds_base) {
  __builtin_amdgcn_global_load_lds(
      (const __attribute__((address_space(1))) unsigned int*)gsrc,
      (__attribute__((address_space(3))) unsigned int*)lds_base, 16, 0, 0);
}

// Stage 1: 1x1 conv projections. q,k -> [B][N][C] bf16 (position-major),
// v -> [B][C][N] bf16 + fp32. q additionally scaled by QSCALE.
__global__ __launch_bounds__(256) void proj_kernel(
    const float* __restrict__ xq, const float* __restrict__ xk, const float* __restrict__ xv,
    const float* __restrict__ Wq, const float* __restrict__ bq,
    const float* __restrict__ Wk, const float* __restrict__ bk,
    const float* __restrict__ Wv, const float* __restrict__ bv,
    unsigned short* __restrict__ qT, unsigned short* __restrict__ kT,
    unsigned short* __restrict__ vb, float* __restrict__ vf)
{
  __shared__ float sW[NC * NC];
  __shared__ float sB[NC];
  const int p = blockIdx.z, b = blockIdx.y;
  const int n0 = blockIdx.x * 128;
  const int tid = threadIdx.x;
  const int wv = tid >> 6, l = tid & 63;

  const float* x    = p == 0 ? xq : (p == 1 ? xk : xv);
  const float* W    = p == 0 ? Wq : (p == 1 ? Wk : Wv);
  const float* bias = p == 0 ? bq : (p == 1 ? bk : bv);

  for (int i = tid; i < NC * NC; i += 256) sW[i] = W[i];
  if (tid < NC) sB[tid] = bias[tid];
  __syncthreads();

  const int nb = n0 + 2 * l;
  const float* xb = x + (size_t)b * NC * NPOS + nb;

  float acc[16][2];
#pragma unroll
  for (int oi = 0; oi < 16; ++oi) {
    float bz = sB[16 * wv + oi];
    acc[oi][0] = bz; acc[oi][1] = bz;
  }
  for (int c = 0; c < NC; ++c) {
    const float2 x2 = *(const float2*)(xb + (size_t)c * NPOS);
#pragma unroll
    for (int oi = 0; oi < 16; ++oi) {
      float wgt = sW[(16 * wv + oi) * NC + c];
      acc[oi][0] = fmaf(wgt, x2.x, acc[oi][0]);
      acc[oi][1] = fmaf(wgt, x2.y, acc[oi][1]);
    }
  }

  if (p < 2) {
    const float qs = (p == 0) ? QSCALE : 1.0f;
    unsigned short* dst = (p == 0 ? qT : kT) + (size_t)b * NPOS * NC;
#pragma unroll
    for (int r = 0; r < 2; ++r) {
      uint4 w0, w1;
      w0.x = pack2(qs * acc[0][r],  qs * acc[1][r]);
      w0.y = pack2(qs * acc[2][r],  qs * acc[3][r]);
      w0.z = pack2(qs * acc[4][r],  qs * acc[5][r]);
      w0.w = pack2(qs * acc[6][r],  qs * acc[7][r]);
      w1.x = pack2(qs * acc[8][r],  qs * acc[9][r]);
      w1.y = pack2(qs * acc[10][r], qs * acc[11][r]);
      w1.z = pack2(qs * acc[12][r], qs * acc[13][r]);
      w1.w = pack2(qs * acc[14][r], qs * acc[15][r]);
      unsigned short* rp = dst + (size_t)(nb + r) * NC + 16 * wv;
      *(uint4*)(rp) = w0;
      *(uint4*)(rp + 8) = w1;
    }
  } else {
#pragma unroll
    for (int oi = 0; oi < 16; ++oi) {
      const int o = 16 * wv + oi;
      float2 v2;
      v2.x = acc[oi][0]; v2.y = acc[oi][1];
      *(float2*)(vf + ((size_t)b * NC + o) * NPOS + nb) = v2;
      *(unsigned*)(vb + ((size_t)b * NC + o) * NPOS + nb) = pack2(acc[oi][0], acc[oi][1]);
    }
  }
}

// Stage 2: flash attention partials. Block = 512 threads (8 waves), 256 cols
// (32 cols/wave via dual K-fragment sets). 2-buffer LDS staging, counted vmcnt.
__global__ __launch_bounds__(512, 4) void attn_partial(
    const unsigned short* __restrict__ qT,
    const unsigned short* __restrict__ kT,
    const unsigned short* __restrict__ vb,
    float* __restrict__ pav, float* __restrict__ plsum)
{
  __shared__ unsigned short qs_[2][64 * 64];   // 8KB each, XOR-swizzled rows
  __shared__ unsigned short vs_[2][64 * 64];
  __shared__ unsigned short pT[8][16][68];     // stride 136B: conflict-free b64 r/w

  const int b = blockIdx.y, z = blockIdx.z;
  const int m0 = blockIdx.x * 256;
  const int tid = threadIdx.x;
  const int w = tid >> 6, l = tid & 63;
  const int lm = l & 15, g = l >> 4;
  const int mA = m0 + 32 * w + lm;       // column set A
  const int mB = mA + 16;                // column set B

  const unsigned short* kbA = kT + (size_t)(b * NPOS + mA) * NC + 8 * g;
  const unsigned short* kbB = kT + (size_t)(b * NPOS + mB) * NC + 8 * g;
  const bf16x8 kb0 = *(const bf16x8*)(kbA);
  const bf16x8 kb1 = *(const bf16x8*)(kbA + 32);
  const bf16x8 kb2 = *(const bf16x8*)(kbB);
  const bf16x8 kb3 = *(const bf16x8*)(kbB + 32);

  const char* qb  = (const char*)(qT + (size_t)b * NPOS * NC);
  const char* vbb = (const char*)(vb + (size_t)b * NC * NPOS);

  // staging geometry: thread t writes 16B at LDS byte t*16 = (row=t>>3, swz col (t&7)*16)
  const int srow = tid >> 3;
  const int slc  = ((tid & 7) * 16) ^ ((srow & 7) << 4);  // inverse-swizzled src col
  const char* qsrc0 = qb + (size_t)srow * 128 + slc;          // + n0*128
  const char* vsrc0 = vbb + (size_t)srow * (NPOS * 2) + slc;  // + n0*2
  const int ldsoff = w * 512;  // shorts; wave-uniform base for global_load_lds

  f32x4 accA[4] = {{0,0,0,0},{0,0,0,0},{0,0,0,0},{0,0,0,0}};
  f32x4 accB[4] = {{0,0,0,0},{0,0,0,0},{0,0,0,0},{0,0,0,0}};
  float lsumA = 0.f, lsumB = 0.f;

  const int nbeg = z * NCHUNK;
  const int iters = NCHUNK >> 6;  // 32, even for all z

  // prologue: stage buffer 0
  gload_lds16(qsrc0 + (size_t)nbeg * 128, &qs_[0][ldsoff]);
  gload_lds16(vsrc0 + (size_t)nbeg * 2,   &vs_[0][ldsoff]);

  const int swz = (lm & 7) << 4;  // read-side swizzle

  int cur = 0;
  for (int t = 0; t < iters; ++t) {
    const int n0 = nbeg + 64 * t;
    // barrier A: everyone finished reading buf cur^1 (iter t-1) -> safe to overwrite
    __builtin_amdgcn_s_barrier();
    if (t + 1 < iters) {
      gload_lds16(qsrc0 + (size_t)(n0 + 64) * 128, &qs_[cur ^ 1][ldsoff]);
      gload_lds16(vsrc0 + (size_t)(n0 + 64) * 2,   &vs_[cur ^ 1][ldsoff]);
      asm volatile("s_waitcnt vmcnt(2)" ::: "memory");  // stage(t) done; t+1 in flight
    } else {
      asm volatile("s_waitcnt vmcnt(0)" ::: "memory");
    }
    // barrier B: all waves' stage(t) complete -> tile readable
    __builtin_amdgcn_s_barrier();
    __builtin_amdgcn_sched_barrier(0);

    const unsigned short* qt = qs_[cur];
    const unsigned short* vt = vs_[cur];

    // QK^T for both column sets; q-fragments feed 4 MFMA each
    f32x4 s0[4], s1[4];
    __builtin_amdgcn_s_setprio(1);
#pragma unroll
    for (int sub = 0; sub < 4; ++sub) {
      const int nl = 16 * sub + lm;
      bf16x8 qa0 = *(const bf16x8*)(qt + nl * 64 + (((16 * g) ^ swz) >> 1));
      bf16x8 qa1 = *(const bf16x8*)(qt + nl * 64 + (((64 + 16 * g) ^ swz) >> 1));
      f32x4 za = {0, 0, 0, 0};
      za = __builtin_amdgcn_mfma_f32_16x16x32_bf16(qa0, kb0, za, 0, 0, 0);
      za = __builtin_amdgcn_mfma_f32_16x16x32_bf16(qa1, kb1, za, 0, 0, 0);
      s0[sub] = za;
      f32x4 zb = {0, 0, 0, 0};
      zb = __builtin_amdgcn_mfma_f32_16x16x32_bf16(qa0, kb2, zb, 0, 0, 0);
      zb = __builtin_amdgcn_mfma_f32_16x16x32_bf16(qa1, kb3, zb, 0, 0, 0);
      s1[sub] = zb;
    }
    __builtin_amdgcn_s_setprio(0);

    // ---- pass A: softmax + PV for column set A; V kept in registers ----
#pragma unroll
    for (int sub = 0; sub < 4; ++sub) {
      float p0 = EXP2F(s0[sub][0]);
      float p1 = EXP2F(s0[sub][1]);
      float p2 = EXP2F(s0[sub][2]);
      float p3 = EXP2F(s0[sub][3]);
      lsumA += (p0 + p1) + (p2 + p3);
      bf16x4 pk;
      pk[0] = (__bf16)p0; pk[1] = (__bf16)p1;
      pk[2] = (__bf16)p2; pk[3] = (__bf16)p3;
      *(bf16x4*)&pT[w][lm][16 * sub + 4 * g] = pk;
    }
    bf16x8 va[2][4];
    __builtin_amdgcn_s_setprio(1);
#pragma unroll
    for (int ks = 0; ks < 2; ++ks) {
      bf16x8 pb = *(const bf16x8*)&pT[w][lm][8 * g + 32 * ks];
#pragma unroll
      for (int cs = 0; cs < 4; ++cs) {
        const int vr = 16 * cs + lm;
        va[ks][cs] = *(const bf16x8*)(vt + vr * 64 + (((16 * g + 64 * ks) ^ swz) >> 1));
        accA[cs] = __builtin_amdgcn_mfma_f32_16x16x32_bf16(va[ks][cs], pb, accA[cs], 0, 0, 0);
      }
    }
    __builtin_amdgcn_s_setprio(0);

    // ---- pass B: softmax + PV for column set B; reuse va registers ----
#pragma unroll
    for (int sub = 0; sub < 4; ++sub) {
      float p0 = EXP2F(s1[sub][0]);
      float p1 = EXP2F(s1[sub][1]);
      float p2 = EXP2F(s1[sub][2]);
      float p3 = EXP2F(s1[sub][3]);
      lsumB += (p0 + p1) + (p2 + p3);
      bf16x4 pk;
      pk[0] = (__bf16)p0; pk[1] = (__bf16)p1;
      pk[2] = (__bf16)p2; pk[3] = (__bf16)p3;
      *(bf16x4*)&pT[w][lm][16 * sub + 4 * g] = pk;
    }
    __builtin_amdgcn_s_setprio(1);
#pragma unroll
    for (int ks = 0; ks < 2; ++ks) {
      bf16x8 pb = *(const bf16x8*)&pT[w][lm][8 * g + 32 * ks];
#pragma unroll
      for (int cs = 0; cs < 4; ++cs) {
        accB[cs] = __builtin_amdgcn_mfma_f32_16x16x32_bf16(va[ks][cs], pb, accB[cs], 0, 0, 0);
      }
    }
    __builtin_amdgcn_s_setprio(0);
    cur ^= 1;
  }

  lsumA += __shfl_xor(lsumA, 16);
  lsumA += __shfl_xor(lsumA, 32);
  lsumB += __shfl_xor(lsumB, 16);
  lsumB += __shfl_xor(lsumB, 32);
  if (l < 16) {
    plsum[((size_t)(z * NB + b) << 13) + mA] = lsumA;
    plsum[((size_t)(z * NB + b) << 13) + mB] = lsumB;
  }

  float* po = pav + ((size_t)((z * NB + b) * NC) << 13);
#pragma unroll
  for (int cs = 0; cs < 4; ++cs) {
#pragma unroll
    for (int r = 0; r < 4; ++r) {
      const int c = 16 * cs + 4 * g + r;
      po[((size_t)c << 13) + mA] = accA[cs][r];
      po[((size_t)c << 13) + mB] = accB[cs][r];
    }
  }
}

// Stage 3: combine partials, normalize, epilogue.
__global__ __launch_bounds__(256) void reduce_kernel(
    const float* __restrict__ pav, const float* __restrict__ plsum,
    const float* __restrict__ vf, const float* __restrict__ gamma_p,
    float* __restrict__ out)
{
  const size_t base = ((size_t)blockIdx.x * 256 + threadIdx.x) * 4;
  const int m = (int)(base & (NPOS - 1));
  const int bc = (int)(base >> 13);       // b*64 + c
  const int b = bc >> 6;

  float4 s = {0, 0, 0, 0};
  float4 L = {0, 0, 0, 0};
#pragma unroll
  for (int zz = 0; zz < NSPLIT; ++zz) {
    const float4 a = *(const float4*)(pav + (((size_t)(zz * NB * NC + bc)) << 13) + m);
    s.x += a.x; s.y += a.y; s.z += a.z; s.w += a.w;
    const float4 q = *(const float4*)(plsum + (((size_t)(zz * NB + b)) << 13) + m);
    L.x += q.x; L.y += q.y; L.z += q.z; L.w += q.w;
  }
  const float gmv = gamma_p[0];
  const float4 v4 = *(const float4*)(vf + base);
  float4 o;
  o.x = gmv * s.x / L.x + v4.x;
  o.y = gmv * s.y / L.y + v4.y;
  o.z = gmv * s.z / L.z + v4.z;
  o.w = gmv * s.w / L.w + v4.w;
  *(float4*)(out + base) = o;
}

extern "C" void kernel_launch(void* const* d_in, const int* in_sizes, int n_in,
                              void* d_out, int out_size, void* d_ws, size_t ws_size,
                              hipStream_t stream) {
  const float* xq = (const float*)d_in[0];
  const float* xk = (const float*)d_in[1];
  const float* xv = (const float*)d_in[2];
  const float* Wq = (const float*)d_in[3];
  const float* bq = (const float*)d_in[4];
  const float* Wk = (const float*)d_in[5];
  const float* bk = (const float*)d_in[6];
  const float* Wv = (const float*)d_in[7];
  const float* bv = (const float*)d_in[8];
  const float* gm = (const float*)d_in[9];
  float* out = (float*)d_out;

  // ws: qT(4MB) | kT(4MB) | v_bf16(4MB) | v_f32(8MB) | pav(32MB) | plsum(512KB)
  unsigned short* qT   = (unsigned short*)d_ws;
  unsigned short* kT   = qT + (size_t)NB * NPOS * NC;
  unsigned short* vbuf = kT + (size_t)NB * NPOS * NC;
  float* vf    = (float*)(vbuf + (size_t)NB * NPOS * NC);
  float* pav   = vf + (size_t)NB * NC * NPOS;
  float* plsum = pav + (size_t)NSPLIT * NB * NC * NPOS;

  hipLaunchKernelGGL(proj_kernel, dim3(64, 4, 3), dim3(256), 0, stream,
                     xq, xk, xv, Wq, bq, Wk, bk, Wv, bv, qT, kT, vbuf, vf);
  hipLaunchKernelGGL(attn_partial, dim3(NPOS / 256, NB, NSPLIT), dim3(512), 0, stream,
                     qT, kT, vbuf, pav, plsum);
  hipLaunchKernelGGL(reduce_kernel, dim3(2048), dim3(256), 0, stream,
                     pav, plsum, vf, gm, out);
}